// Round 1
// baseline (103422.083 us; speedup 1.0000x reference)
//
#include <hip/hip_runtime.h>

#define B_ 512
#define N_ 256
#define D_ 256
#define NEGINF (-1e30)

// ---------------- transpose: out[c][r] = in[r][c], in is R x C ----------------
__global__ void transpose_k(const float* __restrict__ in, float* __restrict__ out,
                            int R, int C) {
  __shared__ float tile[32][33];
  int rb = blockIdx.y * 32, cb = blockIdx.x * 32;
  int tx = threadIdx.x, ty = threadIdx.y;  // block (32,8)
  for (int i = ty; i < 32; i += 8) {
    int r = rb + i, c = cb + tx;
    if (r < R && c < C) tile[i][tx] = in[r * C + c];
  }
  __syncthreads();
  for (int i = ty; i < 32; i += 8) {
    int c = cb + i, r = rb + tx;
    if (r < R && c < C) out[c * R + r] = tile[tx][i];
  }
}

// ---------------- keys: keysT[b][d][n] = bk[d] + sum_c wk[d][c]*enc[b][n][c] --
// fp64 accumulate, fp32 store. wkT is wk transposed: wkT[c][d].
__global__ __launch_bounds__(256) void keys_k(const float* __restrict__ enc,
                                              const float* __restrict__ wkT,
                                              const float* __restrict__ bk,
                                              float* __restrict__ keysT) {
  int b = blockIdx.x;
  int d = threadIdx.x;  // 256 threads, one output-row d each
  __shared__ float encS[32][256];  // 32 n-rows staged
  const float* encB = enc + (size_t)b * N_ * D_;
  float* outB = keysT + (size_t)b * N_ * D_;  // layout [d][n]
  double bkd = (double)bk[d];
  for (int n0 = 0; n0 < N_; n0 += 32) {
    __syncthreads();
    // stage 32x256 fp32 tile, coalesced float4
    {
      const float4* src = (const float4*)(encB + (size_t)n0 * D_);
      float4* dst = (float4*)(&encS[0][0]);
#pragma unroll
      for (int i = 0; i < 8; ++i) dst[threadIdx.x + i * 256] = src[threadIdx.x + i * 256];
    }
    __syncthreads();
    double acc[32];
#pragma unroll
    for (int j = 0; j < 32; ++j) acc[j] = bkd;
    for (int c0 = 0; c0 < 256; c0 += 4) {
      double dw0 = (double)wkT[(c0 + 0) * 256 + d];
      double dw1 = (double)wkT[(c0 + 1) * 256 + d];
      double dw2 = (double)wkT[(c0 + 2) * 256 + d];
      double dw3 = (double)wkT[(c0 + 3) * 256 + d];
#pragma unroll
      for (int j = 0; j < 32; ++j) {
        const float4 e = *(const float4*)&encS[j][c0];  // broadcast read
        acc[j] += dw0 * (double)e.x;
        acc[j] += dw1 * (double)e.y;
        acc[j] += dw2 * (double)e.z;
        acc[j] += dw3 * (double)e.w;
      }
    }
#pragma unroll
    for (int j = 0; j < 32; j += 4) {
      float4 o;
      o.x = (float)acc[j + 0]; o.y = (float)acc[j + 1];
      o.z = (float)acc[j + 2]; o.w = (float)acc[j + 3];
      *(float4*)&outB[d * N_ + n0 + j] = o;
    }
  }
}

// ---------------- persistent decode: one workgroup per batch row --------------
__global__ __launch_bounds__(256) void decode_k(
    const float* __restrict__ enc, const float* __restrict__ init_token,
    const float* __restrict__ b_ih, const float* __restrict__ b_hh,
    const float* __restrict__ bq, const float* __restrict__ wihT,
    const float* __restrict__ whhT, const float* __restrict__ wqT,
    const float* __restrict__ keysT, float* __restrict__ out) {
  const int b = blockIdx.x;
  const int tid = threadIdx.x;  // 256 threads

  __shared__ double xh[2 * D_];  // xh[2d]=x[d], xh[2d+1]=h[d]
  __shared__ double qs[D_];
  __shared__ double lg[N_];
  __shared__ unsigned char maskS[N_];
  __shared__ double redA[4];
  __shared__ double redB[4];
  __shared__ int redI[4];
  __shared__ double s_m, s_logZ;
  __shared__ int s_idx;

  const float* encB = enc + (size_t)b * N_ * D_;
  const float* keysB = keysT + (size_t)b * N_ * D_;

  // init: h = mean_n enc[b][n][:], x = init_token, mask = 1
  {
    double acc = 0.0;
#pragma unroll 4
    for (int n = 0; n < N_; ++n) acc += (double)encB[n * D_ + tid];
    xh[2 * tid + 1] = acc * (1.0 / 256.0);
    xh[2 * tid] = (double)init_token[tid];
    maskS[tid] = 1;
  }
  __syncthreads();

  float* out_t = out + (size_t)b * N_;
  float* out_lp = out + (size_t)B_ * N_ + (size_t)b * N_;
  float* out_en = out + 2 * (size_t)B_ * N_ + (size_t)b * N_;

  const float* wi0 = wihT + tid;
  const float* wh0 = whhT + tid;
  const float* wq0 = wqT + tid;

  for (int t = 0; t < N_; ++t) {
    // ---- GRU: thread computes gate column `tid` for r,z,n ----
    double air = (double)b_ih[tid], aiz = (double)b_ih[D_ + tid], ain = (double)b_ih[2 * D_ + tid];
    double ahr = (double)b_hh[tid], ahz = (double)b_hh[D_ + tid], ahn = (double)b_hh[2 * D_ + tid];
#pragma unroll 4
    for (int d = 0; d < D_; ++d) {
      double xd = xh[2 * d];
      double hd = xh[2 * d + 1];
      const float* wi = wi0 + d * 768;
      const float* wh = wh0 + d * 768;
      air += (double)wi[0] * xd;
      aiz += (double)wi[256] * xd;
      ain += (double)wi[512] * xd;
      ahr += (double)wh[0] * hd;
      ahz += (double)wh[256] * hd;
      ahn += (double)wh[512] * hd;
    }
    double r = 1.0 / (1.0 + exp(-(air + ahr)));
    double z = 1.0 / (1.0 + exp(-(aiz + ahz)));
    double nn = tanh(ain + r * ahn);
    double hold = xh[2 * tid + 1];
    double hnew = (1.0 - z) * nn + z * hold;
    __syncthreads();  // all reads of xh (h) done
    xh[2 * tid + 1] = hnew;
    __syncthreads();

    // ---- query: qs[tid] = bq[tid] + sum_d wq[tid][d]*h[d] ----
    double aq = (double)bq[tid];
#pragma unroll 4
    for (int d = 0; d < D_; ++d) aq += (double)wq0[d * D_] * xh[2 * d + 1];
    qs[tid] = aq;
    __syncthreads();

    // ---- logits for n = tid ----
    double lgv = 0.0;
#pragma unroll 4
    for (int d = 0; d < D_; ++d) lgv += (double)keysB[d * N_ + tid] * qs[d];
    lgv *= 0.0625;  // 1/sqrt(256)
    if (!maskS[tid]) lgv = NEGINF;
    lg[tid] = lgv;

    // ---- max + argmax (first-index tie-break) ----
    double v = lgv;
    int idx = tid;
    for (int off = 32; off > 0; off >>= 1) {
      double ov = __shfl_down(v, off);
      int oi = __shfl_down(idx, off);
      if (ov > v || (ov == v && oi < idx)) { v = ov; idx = oi; }
    }
    int wid = tid >> 6;
    if ((tid & 63) == 0) { redA[wid] = v; redI[wid] = idx; }
    __syncthreads();
    if (tid == 0) {
      double bv = redA[0]; int bi = redI[0];
#pragma unroll
      for (int w = 1; w < 4; ++w)
        if (redA[w] > bv || (redA[w] == bv && redI[w] < bi)) { bv = redA[w]; bi = redI[w]; }
      s_m = bv; s_idx = bi;
    }
    __syncthreads();
    double m = s_m;
    int amax = s_idx;

    // ---- sum exp ----
    double e = exp(lgv - m);  // masked -> exp(-1e30) == 0
    double se = e;
    for (int off = 32; off > 0; off >>= 1) se += __shfl_down(se, off);
    if ((tid & 63) == 0) redB[wid] = se;
    __syncthreads();
    if (tid == 0) s_logZ = m + log(redB[0] + redB[1] + redB[2] + redB[3]);
    __syncthreads();
    double logZ = s_logZ;

    // ---- entropy ----
    double ent = 0.0;
    if (maskS[tid]) {
      double lp = lgv - logZ;
      ent = exp(lp) * lp;
    }
    for (int off = 32; off > 0; off >>= 1) ent += __shfl_down(ent, off);
    __syncthreads();  // redB free for reuse
    if ((tid & 63) == 0) redB[wid] = ent;
    __syncthreads();
    if (tid == 0) {
      double ents = -(redB[0] + redB[1] + redB[2] + redB[3]);
      out_t[t] = (float)amax;
      out_lp[t] = (float)(lg[amax] - logZ);
      out_en[t] = (float)ents;
      maskS[amax] = 0;
    }
    __syncthreads();
    // ---- x <- enc[b][amax][:] ----
    xh[2 * tid] = (double)encB[(size_t)amax * D_ + tid];
    __syncthreads();
  }
}

extern "C" void kernel_launch(void* const* d_in, const int* in_sizes, int n_in,
                              void* d_out, int out_size, void* d_ws, size_t ws_size,
                              hipStream_t stream) {
  const float* enc = (const float*)d_in[0];
  const float* init_token = (const float*)d_in[1];
  const float* w_ih = (const float*)d_in[2];
  const float* w_hh = (const float*)d_in[3];
  const float* b_ih = (const float*)d_in[4];
  const float* b_hh = (const float*)d_in[5];
  const float* wq = (const float*)d_in[6];
  const float* bq = (const float*)d_in[7];
  const float* wk = (const float*)d_in[8];
  const float* bk = (const float*)d_in[9];
  float* out = (float*)d_out;
  float* ws = (float*)d_ws;

  // workspace layout (floats): wkT 64K | wqT 64K | wihT 192K | whhT 192K | keysT 32M
  float* wkT = ws;
  float* wqT = wkT + 65536;
  float* wihT = wqT + 65536;
  float* whhT = wihT + 196608;
  float* keysT = whhT + 196608;
  // total = 34,078,720 floats = 136.3 MB; assume ws_size covers it.

  dim3 tb(32, 8);
  hipLaunchKernelGGL(transpose_k, dim3(8, 8), tb, 0, stream, wk, wkT, 256, 256);
  hipLaunchKernelGGL(transpose_k, dim3(8, 8), tb, 0, stream, wq, wqT, 256, 256);
  hipLaunchKernelGGL(transpose_k, dim3(8, 24), tb, 0, stream, w_ih, wihT, 768, 256);
  hipLaunchKernelGGL(transpose_k, dim3(8, 24), tb, 0, stream, w_hh, whhT, 768, 256);
  hipLaunchKernelGGL(keys_k, dim3(B_), dim3(256), 0, stream, enc, wkT, bk, keysT);
  hipLaunchKernelGGL(decode_k, dim3(B_), dim3(256), 0, stream, enc, init_token,
                     b_ih, b_hh, bq, wihT, whhT, wqT, keysT, out);
}

// Round 2
// 20269.370 us; speedup vs baseline: 5.1024x; 5.1024x over previous
//
#include <hip/hip_runtime.h>

#define B_ 512
#define N_ 256
#define D_ 256
#define NEGINF (-1e30)

// ---------------- transpose: out[c][r] = in[r][c], in is R x C ----------------
__global__ void transpose_k(const float* __restrict__ in, float* __restrict__ out,
                            int R, int C) {
  __shared__ float tile[32][33];
  int rb = blockIdx.y * 32, cb = blockIdx.x * 32;
  int tx = threadIdx.x, ty = threadIdx.y;  // block (32,8)
  for (int i = ty; i < 32; i += 8) {
    int r = rb + i, c = cb + tx;
    if (r < R && c < C) tile[i][tx] = in[r * C + c];
  }
  __syncthreads();
  for (int i = ty; i < 32; i += 8) {
    int c = cb + i, r = rb + tx;
    if (r < R && c < C) out[c * R + r] = tile[tx][i];
  }
}

// ---------------- keys: keysT[b][d][n] = bk[d] + sum_c wk[d][c]*enc[b][n][c] --
__global__ __launch_bounds__(256) void keys_k(const float* __restrict__ enc,
                                              const float* __restrict__ wkT,
                                              const float* __restrict__ bk,
                                              float* __restrict__ keysT) {
  int b = blockIdx.x;
  int d = threadIdx.x;
  __shared__ float encS[32][256];
  const float* encB = enc + (size_t)b * N_ * D_;
  float* outB = keysT + (size_t)b * N_ * D_;
  double bkd = (double)bk[d];
  for (int n0 = 0; n0 < N_; n0 += 32) {
    __syncthreads();
    {
      const float4* src = (const float4*)(encB + (size_t)n0 * D_);
      float4* dst = (float4*)(&encS[0][0]);
#pragma unroll
      for (int i = 0; i < 8; ++i) dst[threadIdx.x + i * 256] = src[threadIdx.x + i * 256];
    }
    __syncthreads();
    double acc[32];
#pragma unroll
    for (int j = 0; j < 32; ++j) acc[j] = bkd;
    for (int c0 = 0; c0 < 256; c0 += 4) {
      double dw0 = (double)wkT[(c0 + 0) * 256 + d];
      double dw1 = (double)wkT[(c0 + 1) * 256 + d];
      double dw2 = (double)wkT[(c0 + 2) * 256 + d];
      double dw3 = (double)wkT[(c0 + 3) * 256 + d];
#pragma unroll
      for (int j = 0; j < 32; ++j) {
        const float4 e = *(const float4*)&encS[j][c0];
        acc[j] += dw0 * (double)e.x;
        acc[j] += dw1 * (double)e.y;
        acc[j] += dw2 * (double)e.z;
        acc[j] += dw3 * (double)e.w;
      }
    }
#pragma unroll
    for (int j = 0; j < 32; j += 4) {
      float4 o;
      o.x = (float)acc[j + 0]; o.y = (float)acc[j + 1];
      o.z = (float)acc[j + 2]; o.w = (float)acc[j + 3];
      *(float4*)&outB[d * N_ + n0 + j] = o;
    }
  }
}

// ---------------- persistent decode: 2 batch rows per block, 1024 threads -----
// thread (s = tid>>8 in [0,4), d = tid&255): 4-way split-K partials in LDS.
__global__ __launch_bounds__(1024, 4) void decode_k(
    const float* __restrict__ enc, const float* __restrict__ init_token,
    const float* __restrict__ b_ih, const float* __restrict__ b_hh,
    const float* __restrict__ bq, const float* __restrict__ wihT,
    const float* __restrict__ whhT, const float* __restrict__ wqT,
    const float* __restrict__ keysT, float* __restrict__ out) {
  const int tid = threadIdx.x;
  const int s = tid >> 8;
  const int d = tid & 255;
  const int b0 = blockIdx.x * 2;

  // partials: a[row][slice][o]; GRU uses o in [0,1024): r,z combined + i_n + h_n
  __shared__ double a[2][4][1024];        // 64 KB
  __shared__ double xh[2][2 * D_];        // x interleaved with h, per row
  __shared__ double qs[2][D_];
  __shared__ double lg[2][N_];
  __shared__ unsigned char maskS[2][N_];
  __shared__ double redA[8];
  __shared__ double redB[8];
  __shared__ int redI[8];
  __shared__ double s_m[2], s_logZ[2];
  __shared__ int s_idx[2];

  const float* encB0 = enc + (size_t)b0 * N_ * D_;
  const float* encB1 = enc + (size_t)(b0 + 1) * N_ * D_;
  const float* keysB0 = keysT + (size_t)b0 * N_ * D_;
  const float* keysB1 = keysT + (size_t)(b0 + 1) * N_ * D_;

  // ---- init: h = mean_n enc[b][n][:], x = init_token, mask = 1 ----
  {
    double p0 = 0.0, p1 = 0.0;
    const float* e0 = encB0 + (size_t)(s * 64) * D_ + d;
    const float* e1 = encB1 + (size_t)(s * 64) * D_ + d;
#pragma unroll 4
    for (int n = 0; n < 64; ++n) {
      p0 += (double)e0[n * D_];
      p1 += (double)e1[n * D_];
    }
    a[0][s][d] = p0;
    a[1][s][d] = p1;
  }
  __syncthreads();
  if (tid < 512) {
    int r = tid >> 8, j = tid & 255;
    double h = (a[r][0][j] + a[r][1][j] + a[r][2][j] + a[r][3][j]) * (1.0 / 256.0);
    xh[r][2 * j + 1] = h;
    xh[r][2 * j] = (double)init_token[j];
    maskS[r][j] = 1;
  }
  __syncthreads();

  for (int t = 0; t < N_; ++t) {
    // ---- phase A: GRU partials (all 1024 threads) ----
    {
      const float* wi = wihT + (size_t)(s * 64) * 768 + d;
      const float* wh = whhT + (size_t)(s * 64) * 768 + d;
      double pr0 = 0, pz0 = 0, pi0 = 0, ph0 = 0;
      double pr1 = 0, pz1 = 0, pi1 = 0, ph1 = 0;
#pragma unroll 4
      for (int dd = 0; dd < 64; ++dd) {
        int c = s * 64 + dd;
        double x0 = xh[0][2 * c], h0 = xh[0][2 * c + 1];
        double x1 = xh[1][2 * c], h1 = xh[1][2 * c + 1];
        double wr = (double)wi[dd * 768];
        double wz = (double)wi[dd * 768 + 256];
        double wn = (double)wi[dd * 768 + 512];
        double vr = (double)wh[dd * 768];
        double vz = (double)wh[dd * 768 + 256];
        double vn = (double)wh[dd * 768 + 512];
        pr0 += wr * x0 + vr * h0;
        pz0 += wz * x0 + vz * h0;
        pi0 += wn * x0;
        ph0 += vn * h0;
        pr1 += wr * x1 + vr * h1;
        pz1 += wz * x1 + vz * h1;
        pi1 += wn * x1;
        ph1 += vn * h1;
      }
      a[0][s][d] = pr0; a[0][s][256 + d] = pz0; a[0][s][512 + d] = pi0; a[0][s][768 + d] = ph0;
      a[1][s][d] = pr1; a[1][s][256 + d] = pz1; a[1][s][512 + d] = pi1; a[1][s][768 + d] = ph1;
    }
    __syncthreads();

    // ---- phase B: reduce + activations + h update (512 threads) ----
    if (tid < 512) {
      int r = tid >> 8, j = tid & 255;
      double sr = a[r][0][j] + a[r][1][j] + a[r][2][j] + a[r][3][j]
                  + (double)b_ih[j] + (double)b_hh[j];
      double sz = a[r][0][256 + j] + a[r][1][256 + j] + a[r][2][256 + j] + a[r][3][256 + j]
                  + (double)b_ih[256 + j] + (double)b_hh[256 + j];
      double si = a[r][0][512 + j] + a[r][1][512 + j] + a[r][2][512 + j] + a[r][3][512 + j]
                  + (double)b_ih[512 + j];
      double sh = a[r][0][768 + j] + a[r][1][768 + j] + a[r][2][768 + j] + a[r][3][768 + j]
                  + (double)b_hh[512 + j];
      double rg = 1.0 / (1.0 + exp(-sr));
      double zg = 1.0 / (1.0 + exp(-sz));
      double nn = tanh(si + rg * sh);
      double hold = xh[r][2 * j + 1];
      xh[r][2 * j + 1] = (1.0 - zg) * nn + zg * hold;
    }
    __syncthreads();

    // ---- phase C: query partials (all threads) ----
    {
      const float* wq = wqT + (size_t)(s * 64) * 256 + d;
      double q0 = 0, q1 = 0;
#pragma unroll 4
      for (int dd = 0; dd < 64; ++dd) {
        int c = s * 64 + dd;
        double w = (double)wq[dd * 256];
        q0 += w * xh[0][2 * c + 1];
        q1 += w * xh[1][2 * c + 1];
      }
      a[0][s][d] = q0;
      a[1][s][d] = q1;
    }
    __syncthreads();

    // ---- phase D: qs reduce (512 threads) ----
    if (tid < 512) {
      int r = tid >> 8, j = tid & 255;
      qs[r][j] = a[r][0][j] + a[r][1][j] + a[r][2][j] + a[r][3][j] + (double)bq[j];
    }
    __syncthreads();

    // ---- phase E: logit partials (all threads; d plays role of n) ----
    {
      const float* k0 = keysB0 + (size_t)(s * 64) * N_ + d;
      const float* k1 = keysB1 + (size_t)(s * 64) * N_ + d;
      double p0 = 0, p1 = 0;
#pragma unroll 4
      for (int dd = 0; dd < 64; ++dd) {
        int c = s * 64 + dd;
        p0 += (double)k0[dd * N_] * qs[0][c];
        p1 += (double)k1[dd * N_] * qs[1][c];
      }
      a[0][s][d] = p0;
      a[1][s][d] = p1;
    }
    __syncthreads();

    // ---- phase F: logits + max/argmax (512 threads; r = tid>>8) ----
    double lgv = NEGINF;
    if (tid < 512) {
      int r = tid >> 8, n = tid & 255;
      lgv = 0.0625 * (a[r][0][n] + a[r][1][n] + a[r][2][n] + a[r][3][n]);
      if (!maskS[r][n]) lgv = NEGINF;
      lg[r][n] = lgv;
      double v = lgv;
      int idx = n;
      for (int off = 32; off > 0; off >>= 1) {
        double ov = __shfl_down(v, off);
        int oi = __shfl_down(idx, off);
        if (ov > v || (ov == v && oi < idx)) { v = ov; idx = oi; }
      }
      if ((tid & 63) == 0) { redA[tid >> 6] = v; redI[tid >> 6] = idx; }
    }
    __syncthreads();
    if ((tid & 255) == 0 && tid < 512) {
      int r = tid >> 8;
      double bv = redA[r * 4]; int bi = redI[r * 4];
#pragma unroll
      for (int w = 1; w < 4; ++w)
        if (redA[r * 4 + w] > bv || (redA[r * 4 + w] == bv && redI[r * 4 + w] < bi)) {
          bv = redA[r * 4 + w]; bi = redI[r * 4 + w];
        }
      s_m[r] = bv; s_idx[r] = bi;
    }
    __syncthreads();

    // ---- phase H: sum exp ----
    if (tid < 512) {
      int r = tid >> 8;
      double se = exp(lgv - s_m[r]);
      for (int off = 32; off > 0; off >>= 1) se += __shfl_down(se, off);
      if ((tid & 63) == 0) redB[tid >> 6] = se;
    }
    __syncthreads();
    if ((tid & 255) == 0 && tid < 512) {
      int r = tid >> 8;
      s_logZ[r] = s_m[r] + log(redB[r * 4] + redB[r * 4 + 1] + redB[r * 4 + 2] + redB[r * 4 + 3]);
    }
    __syncthreads();

    // ---- phase I: entropy ----
    if (tid < 512) {
      int r = tid >> 8, n = tid & 255;
      double ent = 0.0;
      if (maskS[r][n]) {
        double lp = lgv - s_logZ[r];
        ent = exp(lp) * lp;
      }
      for (int off = 32; off > 0; off >>= 1) ent += __shfl_down(ent, off);
      if ((tid & 63) == 0) redB[tid >> 6] = ent;
    }
    __syncthreads();
    // ---- phase J: outputs + mask update ----
    if ((tid & 255) == 0 && tid < 512) {
      int r = tid >> 8;
      double ents = -(redB[r * 4] + redB[r * 4 + 1] + redB[r * 4 + 2] + redB[r * 4 + 3]);
      int am = s_idx[r];
      size_t row = (size_t)(b0 + r) * N_;
      out[row + t] = (float)am;
      out[(size_t)B_ * N_ + row + t] = (float)(lg[r][am] - s_logZ[r]);
      out[2 * (size_t)B_ * N_ + row + t] = (float)ents;
      maskS[r][am] = 0;
    }
    __syncthreads();
    // ---- phase K: x <- enc[b][amax][:] ----
    if (tid < 512) {
      int r = tid >> 8, j = tid & 255;
      const float* encB = (r == 0) ? encB0 : encB1;
      xh[r][2 * j] = (double)encB[(size_t)s_idx[r] * D_ + j];
    }
    __syncthreads();
  }
}

extern "C" void kernel_launch(void* const* d_in, const int* in_sizes, int n_in,
                              void* d_out, int out_size, void* d_ws, size_t ws_size,
                              hipStream_t stream) {
  const float* enc = (const float*)d_in[0];
  const float* init_token = (const float*)d_in[1];
  const float* w_ih = (const float*)d_in[2];
  const float* w_hh = (const float*)d_in[3];
  const float* b_ih = (const float*)d_in[4];
  const float* b_hh = (const float*)d_in[5];
  const float* wq = (const float*)d_in[6];
  const float* bq = (const float*)d_in[7];
  const float* wk = (const float*)d_in[8];
  const float* bk = (const float*)d_in[9];
  float* out = (float*)d_out;
  float* ws = (float*)d_ws;

  // workspace layout (floats): wkT 64K | wqT 64K | wihT 192K | whhT 192K | keysT 32M
  float* wkT = ws;
  float* wqT = wkT + 65536;
  float* wihT = wqT + 65536;
  float* whhT = wihT + 196608;
  float* keysT = whhT + 196608;

  dim3 tb(32, 8);
  hipLaunchKernelGGL(transpose_k, dim3(8, 8), tb, 0, stream, wk, wkT, 256, 256);
  hipLaunchKernelGGL(transpose_k, dim3(8, 8), tb, 0, stream, wq, wqT, 256, 256);
  hipLaunchKernelGGL(transpose_k, dim3(8, 24), tb, 0, stream, w_ih, wihT, 768, 256);
  hipLaunchKernelGGL(transpose_k, dim3(8, 24), tb, 0, stream, w_hh, whhT, 768, 256);
  hipLaunchKernelGGL(keys_k, dim3(B_), dim3(256), 0, stream, enc, wkT, bk, keysT);
  hipLaunchKernelGGL(decode_k, dim3(B_ / 2), dim3(1024), 0, stream, enc, init_token,
                     b_ih, b_hh, bq, wihT, whhT, wqT, keysT, out);
}

// Round 3
// 13879.485 us; speedup vs baseline: 7.4514x; 1.4604x over previous
//
#include <hip/hip_runtime.h>

#define B_ 512
#define N_ 256
#define D_ 256
#define NEGINF (-1e30)

typedef float v4f __attribute__((ext_vector_type(4)));

__device__ __forceinline__ v4f ntload4(const v4f* p) {
  return __builtin_nontemporal_load(p);
}

// pack4C: out4[c4*R + r] = {in[r][4*c4+i]}  (in is R x C, C % 4 == 0)
__global__ __launch_bounds__(256) void pack4C_k(const float* __restrict__ in,
                                                float* __restrict__ out, int R, int C) {
  int o = blockIdx.x * 256 + threadIdx.x;  // o = c4*R + r
  int total = R * (C >> 2);
  if (o >= total) return;
  int r = o % R, c4 = o / R;
  const float4 v = *(const float4*)(in + (size_t)r * C + c4 * 4);
  ((float4*)out)[o] = v;
}

// Wqk[c][e] = sum_d wk[d][c]*wq[d][e]  (fp64), layout double2[e2*256+c] = (e=2*e2, e=2*e2+1)
// bqk[c] = sum_d wk[d][c]*bq[d]
__global__ __launch_bounds__(256) void wqk_k(const float* __restrict__ wk,
                                             const float* __restrict__ wq,
                                             const float* __restrict__ bq,
                                             double* __restrict__ Wqk,
                                             double* __restrict__ bqk) {
  int c = blockIdx.x, e = threadIdx.x;
  double acc = 0.0;
  for (int dd = 0; dd < 256; ++dd)
    acc += (double)wk[dd * 256 + c] * (double)wq[dd * 256 + e];
  Wqk[(e >> 1) * 512 + c * 2 + (e & 1)] = acc;
  if (e == 0) {
    double s = 0.0;
    for (int dd = 0; dd < 256; ++dd) s += (double)wk[dd * 256 + c] * (double)bq[dd];
    bqk[c] = s;
  }
}

// encP[b] as float4 array: encP4[c4*256 + n] = enc[b][n][4*c4..4*c4+3]
__global__ __launch_bounds__(256) void encp_k(const float* __restrict__ enc,
                                              float* __restrict__ encP) {
  int b = blockIdx.y;
  int n0 = blockIdx.x * 64;
  int c = threadIdx.x;
  const float* src = enc + (size_t)b * 65536;
  float* dst = encP + (size_t)b * 65536;
  for (int k = 0; k < 64; ++k) {
    int n = n0 + k;
    dst[(c >> 2) * 1024 + n * 4 + (c & 3)] = src[n * 256 + c];
  }
}

// ---------------- persistent decode: 2 batch rows per block, 1024 threads -----
__global__ __launch_bounds__(1024) void decode_k(
    const float* __restrict__ enc, const float* __restrict__ init_token,
    const float* __restrict__ b_ih, const float* __restrict__ b_hh,
    const float* __restrict__ wihP, const float* __restrict__ whhP,
    const double* __restrict__ Wqk, const double* __restrict__ bqk,
    const float* __restrict__ encP, float* __restrict__ out) {
  const int tid = threadIdx.x;
  const int s = tid >> 8;
  const int d = tid & 255;
  const int b0 = blockIdx.x * 2;

  __shared__ double a[2][4][1024];     // 64 KB split-K partials
  __shared__ double xS[2][D_], hS[2][D_];
  __shared__ double qs[2][D_];
  __shared__ double lg[2][N_];
  __shared__ unsigned char maskS[2][N_];
  __shared__ double redA[8], redB[8], redC[8];
  __shared__ int redI[8];

  const float* encB0 = enc + (size_t)b0 * 65536;
  const float* encB1 = encB0 + 65536;
  const v4f* encP0 = (const v4f*)encP + (size_t)b0 * 16384;
  const v4f* encP1 = encP0 + 16384;
  const v4f* wih4 = (const v4f*)wihP;
  const v4f* whh4 = (const v4f*)whhP;
  const double2* W2 = (const double2*)Wqk;

  // ---- init: h = mean_n enc[b][n][:], x = init_token, mask = 1 ----
  {
    double p0 = 0.0, p1 = 0.0;
    const float* e0 = encB0 + (size_t)(s * 64) * 256 + d;
    const float* e1 = encB1 + (size_t)(s * 64) * 256 + d;
#pragma unroll 4
    for (int n = 0; n < 64; ++n) { p0 += (double)e0[n * 256]; p1 += (double)e1[n * 256]; }
    a[0][s][d] = p0;
    a[1][s][d] = p1;
  }
  __syncthreads();
  if (tid < 512) {
    int r = tid >> 8, j = tid & 255;
    hS[r][j] = (a[r][0][j] + a[r][1][j] + a[r][2][j] + a[r][3][j]) * (1.0 / 256.0);
    xS[r][j] = (double)init_token[j];
    maskS[r][j] = 1;
  }
  __syncthreads();

  for (int t = 0; t < N_; ++t) {
    // ---- A: GRU partials (packed float4 weight loads, L2-resident) ----
    {
      double pr0 = 0, pz0 = 0, pi0 = 0, ph0 = 0;
      double pr1 = 0, pz1 = 0, pi1 = 0, ph1 = 0;
      const int base = s * 16;
#pragma unroll 4
      for (int k = 0; k < 16; ++k) {
        int c4 = base + k;
        int wb = c4 * 768 + d;
        v4f wr = wih4[wb];
        v4f wz = wih4[wb + 256];
        v4f wn = wih4[wb + 512];
        v4f vr = whh4[wb];
        v4f vz = whh4[wb + 256];
        v4f vn = whh4[wb + 512];
        const double* x0 = &xS[0][c4 * 4];
        const double* h0 = &hS[0][c4 * 4];
        const double* x1 = &xS[1][c4 * 4];
        const double* h1 = &hS[1][c4 * 4];
#pragma unroll
        for (int i = 0; i < 4; ++i) {
          double wri = (double)wr[i], wzi = (double)wz[i], wni = (double)wn[i];
          double vri = (double)vr[i], vzi = (double)vz[i], vni = (double)vn[i];
          pr0 += wri * x0[i] + vri * h0[i];
          pz0 += wzi * x0[i] + vzi * h0[i];
          pi0 += wni * x0[i];
          ph0 += vni * h0[i];
          pr1 += wri * x1[i] + vri * h1[i];
          pz1 += wzi * x1[i] + vzi * h1[i];
          pi1 += wni * x1[i];
          ph1 += vni * h1[i];
        }
      }
      a[0][s][d] = pr0; a[0][s][256 + d] = pz0; a[0][s][512 + d] = pi0; a[0][s][768 + d] = ph0;
      a[1][s][d] = pr1; a[1][s][256 + d] = pz1; a[1][s][512 + d] = pi1; a[1][s][768 + d] = ph1;
    }
    __syncthreads();

    // ---- B: reduce + activations + h update ----
    if (tid < 512) {
      int r = tid >> 8, j = tid & 255;
      double sr = a[r][0][j] + a[r][1][j] + a[r][2][j] + a[r][3][j]
                  + (double)b_ih[j] + (double)b_hh[j];
      double sz = a[r][0][256 + j] + a[r][1][256 + j] + a[r][2][256 + j] + a[r][3][256 + j]
                  + (double)b_ih[256 + j] + (double)b_hh[256 + j];
      double si = a[r][0][512 + j] + a[r][1][512 + j] + a[r][2][512 + j] + a[r][3][512 + j]
                  + (double)b_ih[512 + j];
      double sh = a[r][0][768 + j] + a[r][1][768 + j] + a[r][2][768 + j] + a[r][3][768 + j]
                  + (double)b_hh[512 + j];
      double rg = 1.0 / (1.0 + exp(-sr));
      double zg = 1.0 / (1.0 + exp(-sz));
      double nn = tanh(si + rg * sh);
      hS[r][j] = (1.0 - zg) * nn + zg * hS[r][j];
    }
    __syncthreads();

    // ---- C: qk partials = Wqk h + bqk (fp64 double2 loads, L2) ----
    {
      double q0 = (s == 0) ? bqk[d] : 0.0;
      double q1 = q0;
      const int e2b = s * 32;
#pragma unroll 4
      for (int k = 0; k < 32; ++k) {
        int e2 = e2b + k;
        double2 w = W2[e2 * 256 + d];
        q0 += w.x * hS[0][2 * e2] + w.y * hS[0][2 * e2 + 1];
        q1 += w.x * hS[1][2 * e2] + w.y * hS[1][2 * e2 + 1];
      }
      a[0][s][d] = q0;
      a[1][s][d] = q1;
    }
    __syncthreads();

    // ---- D: qk reduce ----
    if (tid < 512) {
      int r = tid >> 8, j = tid & 255;
      qs[r][j] = a[r][0][j] + a[r][1][j] + a[r][2][j] + a[r][3][j];
    }
    __syncthreads();

    // ---- E: logit partials vs encP (nontemporal, L3-resident) ----
    {
      double p0 = 0, p1 = 0;
      const int base = s * 16;
#pragma unroll 2
      for (int k = 0; k < 16; ++k) {
        int c4 = base + k;
        v4f k0 = ntload4(encP0 + c4 * 256 + d);
        v4f k1 = ntload4(encP1 + c4 * 256 + d);
        const double* q0p = &qs[0][c4 * 4];
        const double* q1p = &qs[1][c4 * 4];
#pragma unroll
        for (int i = 0; i < 4; ++i) {
          p0 += (double)k0[i] * q0p[i];
          p1 += (double)k1[i] * q1p[i];
        }
      }
      a[0][s][d] = p0;
      a[1][s][d] = p1;
    }
    __syncthreads();

    // ---- F: logits + wave max/argmax ----
    double lgv = NEGINF, mR = NEGINF;
    int amax = 0;
    if (tid < 512) {
      int r = tid >> 8, n = tid & 255;
      lgv = 0.0625 * (a[r][0][n] + a[r][1][n] + a[r][2][n] + a[r][3][n]);
      if (!maskS[r][n]) lgv = NEGINF;
      lg[r][n] = lgv;
      double v = lgv;
      int idx = n;
#pragma unroll
      for (int off = 32; off > 0; off >>= 1) {
        double ov = __shfl_down(v, off);
        int oi = __shfl_down(idx, off);
        if (ov > v || (ov == v && oi < idx)) { v = ov; idx = oi; }
      }
      if ((tid & 63) == 0) { redA[tid >> 6] = v; redI[tid >> 6] = idx; }
    }
    __syncthreads();

    // ---- G: finalize max (redundant per-thread), S1/S2 reduce, gather x ----
    if (tid < 512) {
      int r = tid >> 8, n = tid & 255;
      double bv = redA[r * 4];
      int bi = redI[r * 4];
#pragma unroll
      for (int w = 1; w < 4; ++w) {
        double wv = redA[r * 4 + w];
        int wi2 = redI[r * 4 + w];
        if (wv > bv || (wv == bv && wi2 < bi)) { bv = wv; bi = wi2; }
      }
      mR = bv;
      amax = bi;
      double e = exp(lgv - mR);        // masked: exp(-1e30) == 0
      double t2 = e * (lgv - mR);      // 0 * finite == 0
      double s1 = e, s2 = t2;
#pragma unroll
      for (int off = 32; off > 0; off >>= 1) {
        s1 += __shfl_down(s1, off);
        s2 += __shfl_down(s2, off);
      }
      if ((tid & 63) == 0) { redB[tid >> 6] = s1; redC[tid >> 6] = s2; }
      const float* encR = (r == 0) ? encB0 : encB1;
      xS[r][n] = (double)__builtin_nontemporal_load(encR + (size_t)amax * 256 + n);
    }
    __syncthreads();

    // ---- H: outputs + mask update ----
    if (tid < 512 && (tid & 255) == 0) {
      int r = tid >> 8;
      double S1 = redB[r * 4] + redB[r * 4 + 1] + redB[r * 4 + 2] + redB[r * 4 + 3];
      double S2 = redC[r * 4] + redC[r * 4 + 1] + redC[r * 4 + 2] + redC[r * 4 + 3];
      double lS = log(S1);
      double logZ = mR + lS;
      size_t row = (size_t)(b0 + r) * N_;
      out[row + t] = (float)amax;
      out[(size_t)B_ * N_ + row + t] = (float)(lg[r][amax] - logZ);
      out[2 * (size_t)B_ * N_ + row + t] = (float)(lS - S2 / S1);
      maskS[r][amax] = 0;
    }
    __syncthreads();
  }
}

extern "C" void kernel_launch(void* const* d_in, const int* in_sizes, int n_in,
                              void* d_out, int out_size, void* d_ws, size_t ws_size,
                              hipStream_t stream) {
  const float* enc = (const float*)d_in[0];
  const float* init_token = (const float*)d_in[1];
  const float* w_ih = (const float*)d_in[2];
  const float* w_hh = (const float*)d_in[3];
  const float* b_ih = (const float*)d_in[4];
  const float* b_hh = (const float*)d_in[5];
  const float* wq = (const float*)d_in[6];
  const float* bq = (const float*)d_in[7];
  const float* wk = (const float*)d_in[8];
  const float* bk = (const float*)d_in[9];  // folded out (shift-invariance); unused
  (void)bk;
  float* out = (float*)d_out;
  char* wsb = (char*)d_ws;

  // ws layout (bytes):
  float* wihP = (float*)(wsb + 0);               // 786,432 B
  float* whhP = (float*)(wsb + 786432);          // 786,432 B
  double* Wqk = (double*)(wsb + 1572864);        // 524,288 B
  double* bqk = (double*)(wsb + 2097152);        // 2,048 B
  float* encP = (float*)(wsb + 2099200);         // 134,217,728 B  (total ~136.3 MB)

  hipLaunchKernelGGL(pack4C_k, dim3(192), dim3(256), 0, stream, w_ih, wihP, 768, 256);
  hipLaunchKernelGGL(pack4C_k, dim3(192), dim3(256), 0, stream, w_hh, whhP, 768, 256);
  hipLaunchKernelGGL(wqk_k, dim3(256), dim3(256), 0, stream, wk, wq, bq, Wqk, bqk);
  hipLaunchKernelGGL(encp_k, dim3(4, 512), dim3(256), 0, stream, enc, encP);
  hipLaunchKernelGGL(decode_k, dim3(B_ / 2), dim3(1024), 0, stream, enc, init_token,
                     b_ih, b_hh, wihP, whhP, Wqk, bqk, encP, out);
}